// Round 3
// baseline (411.702 us; speedup 1.0000x reference)
//
#include <hip/hip_runtime.h>

#define T_STEPS 512
#define BATCH   2048
#define HID     64
#define IN0     8
#define SPW     16                // seqs per wave (MFMA N dim)
#define NBLK    (BATCH / SPW)     // 128 blocks x 1 wave (64 thr)
#define SS      8                 // x-prefetch depth
#define NSS     (T_STEPS / SS)

typedef _Float16 h2 __attribute__((ext_vector_type(2)));
typedef _Float16 h8 __attribute__((ext_vector_type(8)));
typedef float    f4 __attribute__((ext_vector_type(4)));

#define MFMA(a, b, c) __builtin_amdgcn_mfma_f32_16x16x32_f16((a), (b), (c), 0, 0, 0)

union F8 { h8 v; h2 p[4]; };

__device__ __forceinline__ h2 pkrtz(float a, float b) {
    return __builtin_bit_cast(h2, __builtin_amdgcn_cvt_pkrtz(a, b));
}

// tanh(x) = 1 - 2/(exp(2x)+1); saturates correctly at +/-inf.
__device__ __forceinline__ float tanh_fast(float x) {
    float e = __builtin_amdgcn_exp2f(x * 2.885390081777927f);
    return 1.0f - 2.0f * __builtin_amdgcn_rcpf(e + 1.0f);
}

__device__ __forceinline__ h8 load_frag_f16(const float* Wrow) {
    const float4* p = (const float4*)Wrow;
    float4 a = p[0], b = p[1];
    F8 f; f.p[0] = pkrtz(a.x, a.y); f.p[1] = pkrtz(a.z, a.w);
          f.p[2] = pkrtz(b.x, b.y); f.p[3] = pkrtz(b.z, b.w);
    return f.v;
}

// Pack two C tiles (post-tanh) into one B fragment (h8, k-slots j=0..7).
// With the sigma row permutation, j = 4*(mt&1) + r  ->  frag = [tileA, tileB].
__device__ __forceinline__ h8 pack_tanh(const f4 a, const f4 b) {
    F8 f;
    f.p[0] = pkrtz(tanh_fast(a[0]), tanh_fast(a[1]));
    f.p[1] = pkrtz(tanh_fast(a[2]), tanh_fast(a[3]));
    f.p[2] = pkrtz(tanh_fast(b[0]), tanh_fast(b[1]));
    f.p[3] = pkrtz(tanh_fast(b[2]), tanh_fast(b[3]));
    return f.v;
}

// sigma row permutation: C slot (mt, u=4q+r) holds actual H row
//   32*(mt>>1) + 4*(mt&1) + 8*q + r
// => lane(q,n)'s 16 C values are exactly its own next-step B fragment
//    (k = 8q+j natural order), so the recurrence never leaves registers.
__global__ __launch_bounds__(64, 1)
void rnn2_fused(const float* __restrict__ x,
                const float* __restrict__ Wih0, const float* __restrict__ Whh0,
                const float* __restrict__ bih0, const float* __restrict__ bhh0,
                const float* __restrict__ Wih1, const float* __restrict__ Whh1,
                const float* __restrict__ bih1, const float* __restrict__ bhh1,
                const float* __restrict__ fcw,  const float* __restrict__ fcb,
                float* __restrict__ out) {
    const int lane = threadIdx.x;   // single wave
    const int n    = lane & 15;     // seq column; also A row-slot
    const int q    = lane >> 4;
    const int bseq = blockIdx.x * SPW;

    const h2 z2 = pkrtz(0.f, 0.f);

    // ---- sigma-permuted weight fragments, all four matrices in registers ----
    h8 wh0[4][2], wa1[4][2], wb1[4][2], wi0[4];
    f4 b0c[4], b1c[4];
    #pragma unroll
    for (int mt = 0; mt < 4; ++mt) {
        const int ar = 32 * (mt >> 1) + 4 * (mt & 1) + 8 * (n >> 2) + (n & 3);
        #pragma unroll
        for (int kt = 0; kt < 2; ++kt) {
            wh0[mt][kt] = load_frag_f16(Whh0 + ar * HID + 32 * kt + 8 * q);
            wa1[mt][kt] = load_frag_f16(Wih1 + ar * HID + 32 * kt + 8 * q);
            wb1[mt][kt] = load_frag_f16(Whh1 + ar * HID + 32 * kt + 8 * q);
        }
        const float2 ww = *(const float2*)(Wih0 + ar * IN0 + 2 * q);
        F8 f; f.p[0] = pkrtz(ww.x, ww.y); f.p[1] = z2; f.p[2] = z2; f.p[3] = z2;
        wi0[mt] = f.v;
        #pragma unroll
        for (int r = 0; r < 4; ++r) {
            const int cr = 32 * (mt >> 1) + 4 * (mt & 1) + 8 * q + r;
            b0c[mt][r] = bih0[cr] + bhh0[cr];
            b1c[mt][r] = bih1[cr] + bhh1[cr];
        }
    }

    const float* xrow = x + ((size_t)(bseq + n)) * T_STEPS * IN0 + 2 * q;

    h8 hb0[2] = {}, hb1[2] = {};   // B-frags of H0(t-1), H1(t-2)
    f4 a0x[4];                     // bias0 + Wih0@x(t), one step ahead
    {
        const float2 x0 = *(const float2*)xrow;
        F8 xf; xf.p[0] = pkrtz(x0.x, x0.y); xf.p[1] = z2; xf.p[2] = z2; xf.p[3] = z2;
        #pragma unroll
        for (int mt = 0; mt < 4; ++mt) a0x[mt] = MFMA(wi0[mt], xf.v, b0c[mt]);
    }
    float2 xb[SS];
    #pragma unroll
    for (int i = 0; i < SS; ++i) {
        int tn = i + 1; if (tn > T_STEPS - 1) tn = T_STEPS - 1;
        xb[i] = *(const float2*)(xrow + tn * IN0);
    }

    for (int s = 0; s < NSS; ++s) {
        #pragma unroll
        for (int i = 0; i < SS; ++i) {
            const int t = SS * s + i;
            // L0: H0(t) = tanh(a0x + Whh0 @ H0(t-1))  — the critical chain
            f4 c0[4];
            #pragma unroll
            for (int mt = 0; mt < 4; ++mt) {
                c0[mt] = MFMA(wh0[mt][0], hb0[0], a0x[mt]);
                c0[mt] = MFMA(wh0[mt][1], hb0[1], c0[mt]);
            }
            // L1: H1(t-1) = tanh(b1 + Wih1 @ H0(t-1) + Whh1 @ H1(t-2))
            f4 c1[4];
            #pragma unroll
            for (int mt = 0; mt < 4; ++mt) {
                c1[mt] = MFMA(wa1[mt][0], hb0[0], b1c[mt]);
                c1[mt] = MFMA(wa1[mt][1], hb0[1], c1[mt]);
                c1[mt] = MFMA(wb1[mt][0], hb1[0], c1[mt]);
                c1[mt] = MFMA(wb1[mt][1], hb1[1], c1[mt]);
            }
            // a0x(t+1) + refill xb[i] for step t+1+SS (7 steps to land)
            {
                F8 xf; xf.p[0] = pkrtz(xb[i].x, xb[i].y);
                xf.p[1] = z2; xf.p[2] = z2; xf.p[3] = z2;
                #pragma unroll
                for (int mt = 0; mt < 4; ++mt) a0x[mt] = MFMA(wi0[mt], xf.v, b0c[mt]);
                int tn = t + 1 + SS; if (tn > T_STEPS - 1) tn = T_STEPS - 1;
                xb[i] = *(const float2*)(xrow + tn * IN0);
            }
            // fragment updates — in-register, sigma makes layout line up
            hb0[0] = pack_tanh(c0[0], c0[1]);
            hb0[1] = pack_tanh(c0[2], c0[3]);
            if (t == 0) {
                h8 z = {}; hb1[0] = z; hb1[1] = z;   // true H1(-1) = 0
            } else {
                hb1[0] = pack_tanh(c1[0], c1[1]);
                hb1[1] = pack_tanh(c1[2], c1[3]);
            }
        }
    }

    // ---- epilogue: H1(511) from hb0=H0(511), hb1=H1(510); FC head ----
    float sacc = 0.f;
    #pragma unroll
    for (int mt = 0; mt < 4; ++mt) {
        f4 c = MFMA(wa1[mt][0], hb0[0], b1c[mt]);
        c    = MFMA(wa1[mt][1], hb0[1], c);
        c    = MFMA(wb1[mt][0], hb1[0], c);
        c    = MFMA(wb1[mt][1], hb1[1], c);
        #pragma unroll
        for (int r = 0; r < 4; ++r) {
            const int cr = 32 * (mt >> 1) + 4 * (mt & 1) + 8 * q + r;
            sacc += fcw[cr] * tanh_fast(c[r]);
        }
    }
    sacc += __shfl_xor(sacc, 16, 64);
    sacc += __shfl_xor(sacc, 32, 64);
    if (lane < 16) out[bseq + lane] = sacc + fcb[0];
}

extern "C" void kernel_launch(void* const* d_in, const int* in_sizes, int n_in,
                              void* d_out, int out_size, void* d_ws, size_t ws_size,
                              hipStream_t stream) {
    const float* x    = (const float*)d_in[0];
    const float* Wih0 = (const float*)d_in[1];
    const float* Whh0 = (const float*)d_in[2];
    const float* bih0 = (const float*)d_in[3];
    const float* bhh0 = (const float*)d_in[4];
    const float* Wih1 = (const float*)d_in[5];
    const float* Whh1 = (const float*)d_in[6];
    const float* bih1 = (const float*)d_in[7];
    const float* bhh1 = (const float*)d_in[8];
    const float* fcw  = (const float*)d_in[9];
    const float* fcb  = (const float*)d_in[10];
    float* out = (float*)d_out;

    rnn2_fused<<<dim3(NBLK), dim3(64), 0, stream>>>(
        x, Wih0, Whh0, bih0, bhh0, Wih1, Whh1, bih1, bhh1, fcw, fcb, out);
}

// Round 4
// 334.885 us; speedup vs baseline: 1.2294x; 1.2294x over previous
//
#include <hip/hip_runtime.h>

#define T_STEPS 512
#define BATCH   2048
#define HID     64
#define IN0     8
#define SPW     16                // seqs per block (MFMA N dim)
#define NBLK    (BATCH / SPW)     // 128 blocks x 2 waves (128 thr)
#define GS      8                 // steps per pipeline group (ring half depth)
#define NG      (T_STEPS / GS)    // 64 groups

typedef _Float16 h2 __attribute__((ext_vector_type(2)));
typedef _Float16 h8 __attribute__((ext_vector_type(8)));
typedef float    f4 __attribute__((ext_vector_type(4)));

#define MFMA(a, b, c) __builtin_amdgcn_mfma_f32_16x16x32_f16((a), (b), (c), 0, 0, 0)

union F8 { h8 v; h2 p[4]; };

__device__ __forceinline__ h2 pkrtz(float a, float b) {
    return __builtin_bit_cast(h2, __builtin_amdgcn_cvt_pkrtz(a, b));
}

// tanh(x) = 1 - 2/(exp(2x)+1); saturates correctly at +/-inf.
__device__ __forceinline__ float tanh_fast(float x) {
    float e = __builtin_amdgcn_exp2f(x * 2.885390081777927f);
    return 1.0f - 2.0f * __builtin_amdgcn_rcpf(e + 1.0f);
}

__device__ __forceinline__ f4 tanh4(const f4 a) {
    f4 r;
    r[0] = tanh_fast(a[0]); r[1] = tanh_fast(a[1]);
    r[2] = tanh_fast(a[2]); r[3] = tanh_fast(a[3]);
    return r;
}

// pack two post-tanh f4 tiles into one B fragment (sigma layout)
__device__ __forceinline__ h8 pack2(const f4 a, const f4 b) {
    F8 f;
    f.p[0] = pkrtz(a[0], a[1]); f.p[1] = pkrtz(a[2], a[3]);
    f.p[2] = pkrtz(b[0], b[1]); f.p[3] = pkrtz(b[2], b[3]);
    return f.v;
}

__device__ __forceinline__ h8 load_frag_f16(const float* Wrow) {
    const float4* p = (const float4*)Wrow;
    float4 a = p[0], b = p[1];
    F8 f; f.p[0] = pkrtz(a.x, a.y); f.p[1] = pkrtz(a.z, a.w);
          f.p[2] = pkrtz(b.x, b.y); f.p[3] = pkrtz(b.z, b.w);
    return f.v;
}

// Barrier draining ONLY lgkmcnt (LDS); x-prefetch globals stay in flight.
#define LDS_BARRIER() asm volatile("s_waitcnt lgkmcnt(0)\n\ts_barrier" ::: "memory")

// sigma row permutation: C slot (mt, 4q+r) holds actual H row
//   32*(mt>>1) + 4*(mt&1) + 8*q + r
// => each lane's 16 C values are exactly its own next-step B fragment,
//    so each layer's recurrence never leaves registers (verified R2).
__global__ __launch_bounds__(128, 1)
void rnn2_pipe(const float* __restrict__ x,
               const float* __restrict__ Wih0, const float* __restrict__ Whh0,
               const float* __restrict__ bih0, const float* __restrict__ bhh0,
               const float* __restrict__ Wih1, const float* __restrict__ Whh1,
               const float* __restrict__ bih1, const float* __restrict__ bhh1,
               const float* __restrict__ fcw,  const float* __restrict__ fcb,
               float* __restrict__ out) {
    const int tid  = threadIdx.x;
    const int w    = tid >> 6;      // wave 0: layer0 producer; wave 1: layer1 consumer
    const int lane = tid & 63;
    const int n    = lane & 15;     // seq column
    const int q    = lane >> 4;
    const int bseq = blockIdx.x * SPW;

    // H0 ring: 2 halves x GS steps x 2 frags x 64 lanes x 16B = 32 KB.
    // 16B/lane contiguous -> conflict-free ds_read/write_b128.
    __shared__ h8 ring[2][GS][2][64];

    const h2 z2 = pkrtz(0.f, 0.f);
    const f4 zero = {0.f, 0.f, 0.f, 0.f};

    h8 wh0[4][2], wi0[4];           // wave A
    h8 wa1[4][2], wb1[4][2];        // wave B
    f4 b0c[4], b1c[4], fcv[4];

    if (w == 0) {
        #pragma unroll
        for (int mt = 0; mt < 4; ++mt) {
            const int ar = 32 * (mt >> 1) + 4 * (mt & 1) + 8 * (n >> 2) + (n & 3);
            #pragma unroll
            for (int kt = 0; kt < 2; ++kt)
                wh0[mt][kt] = load_frag_f16(Whh0 + ar * HID + 32 * kt + 8 * q);
            const float2 ww = *(const float2*)(Wih0 + ar * IN0 + 2 * q);
            F8 f; f.p[0] = pkrtz(ww.x, ww.y); f.p[1] = z2; f.p[2] = z2; f.p[3] = z2;
            wi0[mt] = f.v;
            #pragma unroll
            for (int r = 0; r < 4; ++r) {
                const int cr = 32 * (mt >> 1) + 4 * (mt & 1) + 8 * q + r;
                b0c[mt][r] = bih0[cr] + bhh0[cr];
            }
        }
    } else {
        #pragma unroll
        for (int mt = 0; mt < 4; ++mt) {
            const int ar = 32 * (mt >> 1) + 4 * (mt & 1) + 8 * (n >> 2) + (n & 3);
            #pragma unroll
            for (int kt = 0; kt < 2; ++kt) {
                wa1[mt][kt] = load_frag_f16(Wih1 + ar * HID + 32 * kt + 8 * q);
                wb1[mt][kt] = load_frag_f16(Whh1 + ar * HID + 32 * kt + 8 * q);
            }
            #pragma unroll
            for (int r = 0; r < 4; ++r) {
                const int cr = 32 * (mt >> 1) + 4 * (mt & 1) + 8 * q + r;
                b1c[mt][r] = bih1[cr] + bhh1[cr];
                fcv[mt][r] = fcw[cr];
            }
        }
    }
    const float fcb0 = fcb[0];

    const float* xrow = x + ((size_t)(bseq + n)) * T_STEPS * IN0 + 2 * q;

    h8 hb0[2] = {}, hb1[2] = {};    // B-frags: H0(t-1) (A), H1(t-1) (B)
    f4 a0x[4];                      // A: bias0 + Wih0@x(t), one step ahead
    float2 xb[GS];
    if (w == 0) {
        const float2 x0 = *(const float2*)xrow;
        F8 xf; xf.p[0] = pkrtz(x0.x, x0.y); xf.p[1] = z2; xf.p[2] = z2; xf.p[3] = z2;
        #pragma unroll
        for (int mt = 0; mt < 4; ++mt) a0x[mt] = MFMA(wi0[mt], xf.v, b0c[mt]);
        #pragma unroll
        for (int i = 0; i < GS; ++i) {
            int tn = i + 1; if (tn > T_STEPS - 1) tn = T_STEPS - 1;
            xb[i] = *(const float2*)(xrow + tn * IN0);
        }
    }
    float sacc = 0.f;

    // Pipeline: iteration g: A produces group g (steps 8g..8g+7) into half g&1;
    // B consumes group g-1 from half (g-1)&1. One barrier per 8 steps.
    for (int g = 0; g <= NG; ++g) {
        if (w == 0) {
            if (g < NG) {
                #pragma unroll
                for (int i = 0; i < GS; ++i) {
                    const int t = GS * g + i;
                    f4 th[4];
                    #pragma unroll
                    for (int mt = 0; mt < 4; ++mt) {
                        f4 ca = MFMA(wh0[mt][0], hb0[0], a0x[mt]);
                        f4 cb = MFMA(wh0[mt][1], hb0[1], zero);
                        th[mt] = tanh4(ca + cb);
                    }
                    hb0[0] = pack2(th[0], th[1]);
                    hb0[1] = pack2(th[2], th[3]);
                    ring[g & 1][i][0][lane] = hb0[0];
                    ring[g & 1][i][1][lane] = hb0[1];
                    // a0x(t+1) — off the chain
                    F8 xf; xf.p[0] = pkrtz(xb[i].x, xb[i].y);
                    xf.p[1] = z2; xf.p[2] = z2; xf.p[3] = z2;
                    #pragma unroll
                    for (int mt = 0; mt < 4; ++mt)
                        a0x[mt] = MFMA(wi0[mt], xf.v, b0c[mt]);
                    int tn = t + 1 + GS; if (tn > T_STEPS - 1) tn = T_STEPS - 1;
                    xb[i] = *(const float2*)(xrow + tn * IN0);
                }
            }
        } else {
            if (g > 0) {
                const int h = (g - 1) & 1;
                #pragma unroll
                for (int i = 0; i < GS; ++i) {
                    const h8 rb0 = ring[h][i][0][lane];
                    const h8 rb1 = ring[h][i][1][lane];
                    f4 th[4];
                    #pragma unroll
                    for (int mt = 0; mt < 4; ++mt) {
                        f4 c1a = MFMA(wa1[mt][0], rb0,    b1c[mt]);
                        f4 c1b = MFMA(wa1[mt][1], rb1,    zero);
                        f4 c1c = MFMA(wb1[mt][0], hb1[0], zero);
                        f4 c1d = MFMA(wb1[mt][1], hb1[1], zero);
                        th[mt] = tanh4((c1a + c1b) + (c1c + c1d));
                    }
                    hb1[0] = pack2(th[0], th[1]);
                    hb1[1] = pack2(th[2], th[3]);
                    if (g == NG && i == GS - 1) {
                        // H1(511) in f32 (pre-pack) -> FC head
                        #pragma unroll
                        for (int mt = 0; mt < 4; ++mt)
                            #pragma unroll
                            for (int r = 0; r < 4; ++r)
                                sacc += fcv[mt][r] * th[mt][r];
                    }
                }
            }
        }
        LDS_BARRIER();
    }

    if (w == 1) {
        sacc += __shfl_xor(sacc, 16, 64);
        sacc += __shfl_xor(sacc, 32, 64);
        if (lane < 16) out[bseq + lane] = sacc + fcb0;
    }
}

extern "C" void kernel_launch(void* const* d_in, const int* in_sizes, int n_in,
                              void* d_out, int out_size, void* d_ws, size_t ws_size,
                              hipStream_t stream) {
    const float* x    = (const float*)d_in[0];
    const float* Wih0 = (const float*)d_in[1];
    const float* Whh0 = (const float*)d_in[2];
    const float* bih0 = (const float*)d_in[3];
    const float* bhh0 = (const float*)d_in[4];
    const float* Wih1 = (const float*)d_in[5];
    const float* Whh1 = (const float*)d_in[6];
    const float* bih1 = (const float*)d_in[7];
    const float* bhh1 = (const float*)d_in[8];
    const float* fcw  = (const float*)d_in[9];
    const float* fcb  = (const float*)d_in[10];
    float* out = (float*)d_out;

    rnn2_pipe<<<dim3(NBLK), dim3(128), 0, stream>>>(
        x, Wih0, Whh0, bih0, bhh0, Wih1, Whh1, bih1, bhh1, fcw, fcb, out);
}

// Round 5
// 312.897 us; speedup vs baseline: 1.3158x; 1.0703x over previous
//
#include <hip/hip_runtime.h>

#define T_STEPS 512
#define BATCH   2048
#define HID     64
#define IN0     8
#define SPW     16                 // seqs per chain (MFMA N dim)
#define CPB     2                  // chains per block (stall-filling)
#define NBLK    (BATCH / (SPW*CPB))  // 64 blocks x 16 waves (1024 thr)
#define SS      8                  // x-prefetch depth
#define NSS     (T_STEPS / SS)

typedef _Float16 h2 __attribute__((ext_vector_type(2)));
typedef _Float16 h4 __attribute__((ext_vector_type(4)));
typedef _Float16 h8 __attribute__((ext_vector_type(8)));
typedef float    f4 __attribute__((ext_vector_type(4)));

#define MFMA(a, b, c) __builtin_amdgcn_mfma_f32_16x16x32_f16((a), (b), (c), 0, 0, 0)

union F8 { h8 v; h2 p[4]; };
union H4U { h4 v; h2 p[2]; };

__device__ __forceinline__ h2 pkrtz(float a, float b) {
    return __builtin_bit_cast(h2, __builtin_amdgcn_cvt_pkrtz(a, b));
}

// tanh(x) = 1 - 2/(exp(2x)+1); saturates correctly at +/-inf.
__device__ __forceinline__ float tanh_fast(float x) {
    float e = __builtin_amdgcn_exp2f(x * 2.885390081777927f);
    return 1.0f - 2.0f * __builtin_amdgcn_rcpf(e + 1.0f);
}

__device__ __forceinline__ h8 load_frag_f16(const float* Wrow) {
    const float4* p = (const float4*)Wrow;
    float4 a = p[0], b = p[1];
    F8 f; f.p[0] = pkrtz(a.x, a.y); f.p[1] = pkrtz(a.z, a.w);
          f.p[2] = pkrtz(b.x, b.y); f.p[3] = pkrtz(b.z, b.w);
    return f.v;
}

// Barrier draining ONLY lgkmcnt (LDS); x-prefetch globals stay in flight.
#define LDS_BARRIER() asm volatile("s_waitcnt lgkmcnt(0)\n\ts_barrier" ::: "memory")

// 16 waves = 2 independent chains x (4 L0-quarter + 4 L1-quarter waves).
// SIMD w&3 hosts {c0-L0, c0-L1, c1-L0, c1-L1}: chain A's stalls are filled
// by chain B's issue. Both chains share the per-step block barrier.
__global__ __launch_bounds__(1024, 1)
void rnn2_x2(const float* __restrict__ x,
             const float* __restrict__ Wih0, const float* __restrict__ Whh0,
             const float* __restrict__ bih0, const float* __restrict__ bhh0,
             const float* __restrict__ Wih1, const float* __restrict__ Whh1,
             const float* __restrict__ bih1, const float* __restrict__ bhh1,
             const float* __restrict__ fcw,  const float* __restrict__ fcb,
             float* __restrict__ out) {
    const int tid  = threadIdx.x;
    const int w    = tid >> 6;
    const int c    = w >> 3;       // chain 0 / 1
    const int wl   = w & 7;        // role within chain
    const int mt   = wl & 3;       // m-tile (H rows 16mt..16mt+15)
    const bool L0  = (wl < 4);     // 0-3: layer0; 4-7: layer1
    const int lane = tid & 63;
    const int n    = lane & 15;    // B/C column = sequence
    const int q    = lane >> 4;
    const int bseq = blockIdx.x * (SPW * CPB) + c * SPW;

    // Per-chain H buffers [n][k], k-stride 72 (+8 pad); double-buffered by t&1.
    __shared__ __align__(16) _Float16 H0b[CPB][2][SPW * 72];
    __shared__ __align__(16) _Float16 H1b[CPB][2][SPW * 72];
    __shared__ float red[CPB][4][SPW];

    const int widx  = n * 72 + mt * 16 + q * 4;   // C rows k=16mt+4q+r
    const int ridx0 = n * 72 + 0 * 32 + q * 8;    // B-frag slices
    const int ridx1 = n * 72 + 1 * 32 + q * 8;

    const f4 zero = {0.f, 0.f, 0.f, 0.f};
    const h2 z2 = pkrtz(0.f, 0.f);

    // ---- per-role weight fragments (slot j <-> k = 32kt+8q+j) ----
    h8 wa[2], wb[2], wi0;          // L0: wa=Whh0 | L1: wa=Wih1, wb=Whh1
    f4 biasc, fcv;
    const int row = 16 * mt + n;
    if (L0) {
        #pragma unroll
        for (int kt = 0; kt < 2; ++kt)
            wa[kt] = load_frag_f16(Whh0 + row * HID + 32 * kt + 8 * q);
        const float2 ww = *(const float2*)(Wih0 + row * IN0 + 2 * q);
        F8 f; f.p[0] = pkrtz(ww.x, ww.y); f.p[1] = z2; f.p[2] = z2; f.p[3] = z2;
        wi0 = f.v;
        #pragma unroll
        for (int r = 0; r < 4; ++r) {
            const int i = 16 * mt + 4 * q + r;
            biasc[r] = bih0[i] + bhh0[i];
        }
    } else {
        #pragma unroll
        for (int kt = 0; kt < 2; ++kt) {
            wa[kt] = load_frag_f16(Wih1 + row * HID + 32 * kt + 8 * q);
            wb[kt] = load_frag_f16(Whh1 + row * HID + 32 * kt + 8 * q);
        }
        #pragma unroll
        for (int r = 0; r < 4; ++r) {
            const int i = 16 * mt + 4 * q + r;
            biasc[r] = bih1[i] + bhh1[i];
            fcv[r]   = fcw[i];
        }
    }
    const float fcb0 = fcb[0];

    const float* xrow = x + ((size_t)(bseq + n) * T_STEPS) * IN0 + 2 * q;

    h8 h0f[2] = {}, h1f[2] = {};   // H0(t-1); (L1 only) H1(t-2)
    f4 a0x;                        // L0: bias0 + Wih0@x(t), one step ahead
    float2 xb[SS];                 // rolling x prefetch (L0 only)
    if (L0) {
        const float2 x0 = *(const float2*)xrow;
        F8 xf; xf.p[0] = pkrtz(x0.x, x0.y); xf.p[1] = z2; xf.p[2] = z2; xf.p[3] = z2;
        a0x = MFMA(wi0, xf.v, biasc);
        #pragma unroll
        for (int i = 0; i < SS; ++i) {
            int tn = i + 1; if (tn > T_STEPS - 1) tn = T_STEPS - 1;
            xb[i] = *(const float2*)(xrow + tn * IN0);
        }
    }

    for (int s = 0; s < NSS; ++s) {
        #pragma unroll
        for (int i = 0; i < SS; ++i) {
            const int t = SS * s + i;
            const int bf = t & 1;
            if (L0) {
                // H0(t) = tanh(a0x + Whh0@H0(t-1)); independent accumulators
                f4 p0 = MFMA(wa[0], h0f[0], a0x);
                f4 p1 = MFMA(wa[1], h0f[1], zero);
                const f4 a0 = p0 + p1;
                H4U u;
                u.p[0] = pkrtz(tanh_fast(a0[0]), tanh_fast(a0[1]));
                u.p[1] = pkrtz(tanh_fast(a0[2]), tanh_fast(a0[3]));
                *(h4*)&H0b[c][bf][widx] = u.v;
                // a0x(t+1) — off the chain; rolling refill (7 steps to land)
                F8 xf; xf.p[0] = pkrtz(xb[i].x, xb[i].y);
                xf.p[1] = z2; xf.p[2] = z2; xf.p[3] = z2;
                a0x = MFMA(wi0, xf.v, biasc);
                int tn = t + 1 + SS; if (tn > T_STEPS - 1) tn = T_STEPS - 1;
                xb[i] = *(const float2*)(xrow + tn * IN0);
            } else {
                // H1(t-1) = tanh(b1 + Wih1@H0(t-1) + Whh1@H1(t-2))
                f4 c0 = MFMA(wa[0], h0f[0], biasc);
                f4 c1 = MFMA(wa[1], h0f[1], zero);
                f4 c2 = MFMA(wb[0], h1f[0], zero);
                f4 c3 = MFMA(wb[1], h1f[1], zero);
                const f4 a1 = (c0 + c1) + (c2 + c3);
                H4U u;
                u.p[0] = pkrtz(tanh_fast(a1[0]), tanh_fast(a1[1]));
                u.p[1] = pkrtz(tanh_fast(a1[2]), tanh_fast(a1[3]));
                if (t == 0) { u.p[0] = z2; u.p[1] = z2; }   // true H1(-1)=0
                *(h4*)&H1b[c][bf][widx] = u.v;
            }
            LDS_BARRIER();
            h0f[0] = *(const h8*)&H0b[c][bf][ridx0];
            h0f[1] = *(const h8*)&H0b[c][bf][ridx1];
            if (!L0) {
                h1f[0] = *(const h8*)&H1b[c][bf][ridx0];
                h1f[1] = *(const h8*)&H1b[c][bf][ridx1];
            }
        }
    }

    // ---- epilogue: H1(511) from h0f=H0(511), h1f=H1(510); FC head ----
    if (!L0) {
        f4 c0 = MFMA(wa[0], h0f[0], biasc);
        f4 c1 = MFMA(wa[1], h0f[1], zero);
        f4 c2 = MFMA(wb[0], h1f[0], zero);
        f4 c3 = MFMA(wb[1], h1f[1], zero);
        const f4 a1 = (c0 + c1) + (c2 + c3);
        float sacc = 0.f;
        #pragma unroll
        for (int r = 0; r < 4; ++r) sacc += fcv[r] * tanh_fast(a1[r]);
        sacc += __shfl_xor(sacc, 16, 64);
        sacc += __shfl_xor(sacc, 32, 64);
        if (lane < 16) red[c][mt][n] = sacc;    // q==0 lanes
    }
    __syncthreads();
    if (tid < SPW * CPB) {
        const int cc = tid >> 4, nn = tid & 15;
        out[blockIdx.x * (SPW * CPB) + tid] =
            red[cc][0][nn] + red[cc][1][nn] + red[cc][2][nn] + red[cc][3][nn] + fcb0;
    }
}

extern "C" void kernel_launch(void* const* d_in, const int* in_sizes, int n_in,
                              void* d_out, int out_size, void* d_ws, size_t ws_size,
                              hipStream_t stream) {
    const float* x    = (const float*)d_in[0];
    const float* Wih0 = (const float*)d_in[1];
    const float* Whh0 = (const float*)d_in[2];
    const float* bih0 = (const float*)d_in[3];
    const float* bhh0 = (const float*)d_in[4];
    const float* Wih1 = (const float*)d_in[5];
    const float* Whh1 = (const float*)d_in[6];
    const float* bih1 = (const float*)d_in[7];
    const float* bhh1 = (const float*)d_in[8];
    const float* fcw  = (const float*)d_in[9];
    const float* fcb  = (const float*)d_in[10];
    float* out = (float*)d_out;

    rnn2_x2<<<dim3(NBLK), dim3(1024), 0, stream>>>(
        x, Wih0, Whh0, bih0, bhh0, Wih1, Whh1, bih1, bhh1, fcw, fcb, out);
}

// Round 6
// 235.403 us; speedup vs baseline: 1.7489x; 1.3292x over previous
//
#include <hip/hip_runtime.h>

#define T_STEPS 512
#define BATCH   2048
#define HID     64
#define IN0     8
#define SPW     16                // distinct seqs per block (MFMA N dim)
#define NBLK    (BATCH / SPW)     // 128 blocks x 8 waves (512 thr)
#define SS      8                 // x-prefetch depth
#define NSS     (T_STEPS / SS)

typedef _Float16 h2 __attribute__((ext_vector_type(2)));
typedef _Float16 h4 __attribute__((ext_vector_type(4)));
typedef _Float16 h8 __attribute__((ext_vector_type(8)));
typedef float    f4 __attribute__((ext_vector_type(4)));

#define MFMA(a, b, c) __builtin_amdgcn_mfma_f32_16x16x32_f16((a), (b), (c), 0, 0, 0)

union F8 { h8 v; h2 p[4]; };
union H4U { h4 v; h2 p[2]; };
union H8U { h8 v; h4 h[2]; };

__device__ __forceinline__ h2 pkrtz(float a, float b) {
    return __builtin_bit_cast(h2, __builtin_amdgcn_cvt_pkrtz(a, b));
}

// tanh(x) = 1 - 2/(exp(2x)+1); saturates correctly at +/-inf.
__device__ __forceinline__ float tanh_fast(float x) {
    float e = __builtin_amdgcn_exp2f(x * 2.885390081777927f);
    return 1.0f - 2.0f * __builtin_amdgcn_rcpf(e + 1.0f);
}

__device__ __forceinline__ h8 load_frag_f16(const float* Wrow) {
    const float4* p = (const float4*)Wrow;
    float4 a = p[0], b = p[1];
    F8 f; f.p[0] = pkrtz(a.x, a.y); f.p[1] = pkrtz(a.z, a.w);
          f.p[2] = pkrtz(b.x, b.y); f.p[3] = pkrtz(b.z, b.w);
    return f.v;
}

// Barrier draining ONLY lgkmcnt (LDS); x-prefetch globals stay in flight.
#define LDS_BARRIER() asm volatile("s_waitcnt lgkmcnt(0)\n\ts_barrier" ::: "memory")

// H exchange layout: [chunk][n] where chunk c = H rows 4c..4c+3 (one lane's
// packed h4). addr = (16c+n)*8 -> bank slot = n for every access pattern:
//   write (L0 wave mt, lane(q,n)): c = 4mt+q        -> slot n, conflict-free
//   read  (B-frag k-tile kt):      c = 8kt+2q, +1   -> slot n, conflict-free,
//     and the two chunks are 128B apart -> mergeable into ds_read2_b64.
// Replaces the [n][k] stride-72 tile whose read burst cost 2^23 conflict
// cycles per dispatch (measured R1/R4).
__global__ __launch_bounds__(512, 1)
void rnn2_cf(const float* __restrict__ x,
             const float* __restrict__ Wih0, const float* __restrict__ Whh0,
             const float* __restrict__ bih0, const float* __restrict__ bhh0,
             const float* __restrict__ Wih1, const float* __restrict__ Whh1,
             const float* __restrict__ bih1, const float* __restrict__ bhh1,
             const float* __restrict__ fcw,  const float* __restrict__ fcb,
             float* __restrict__ out) {
    const int tid  = threadIdx.x;
    const int w    = tid >> 6;
    const int mt   = w & 3;        // m-tile (H rows 16mt..16mt+15)
    const bool L0  = (w < 4);      // waves 0-3: layer0; waves 4-7: layer1
    const int lane = tid & 63;
    const int n    = lane & 15;    // B/C column = sequence (16 distinct)
    const int q    = lane >> 4;
    const int bseq = blockIdx.x * SPW;

    __shared__ __align__(16) h4 H0c[2][16][16];   // [bf][chunk][n], 4 KB
    __shared__ __align__(16) h4 H1c[2][16][16];
    __shared__ float red[4][SPW];

    const int wc = 4 * mt + q;     // this wave's write chunk

    const f4 zero = {0.f, 0.f, 0.f, 0.f};
    const h2 z2 = pkrtz(0.f, 0.f);

    // ---- per-role weight fragments (slot j <-> k = 32kt+8q+j) ----
    h8 wa[2], wb[2], wi0;          // L0: wa=Whh0 | L1: wa=Wih1, wb=Whh1
    f4 biasc, fcv;
    const int row = 16 * mt + n;
    if (L0) {
        #pragma unroll
        for (int kt = 0; kt < 2; ++kt)
            wa[kt] = load_frag_f16(Whh0 + row * HID + 32 * kt + 8 * q);
        const float2 ww = *(const float2*)(Wih0 + row * IN0 + 2 * q);
        F8 f; f.p[0] = pkrtz(ww.x, ww.y); f.p[1] = z2; f.p[2] = z2; f.p[3] = z2;
        wi0 = f.v;
        #pragma unroll
        for (int r = 0; r < 4; ++r) {
            const int i = 16 * mt + 4 * q + r;
            biasc[r] = bih0[i] + bhh0[i];
        }
    } else {
        #pragma unroll
        for (int kt = 0; kt < 2; ++kt) {
            wa[kt] = load_frag_f16(Wih1 + row * HID + 32 * kt + 8 * q);
            wb[kt] = load_frag_f16(Whh1 + row * HID + 32 * kt + 8 * q);
        }
        #pragma unroll
        for (int r = 0; r < 4; ++r) {
            const int i = 16 * mt + 4 * q + r;
            biasc[r] = bih1[i] + bhh1[i];
            fcv[r]   = fcw[i];
        }
    }
    const float fcb0 = fcb[0];

    const float* xrow = x + ((size_t)(bseq + n) * T_STEPS) * IN0 + 2 * q;

    h8 h0f[2] = {}, h1f[2] = {};   // H0(t-1); (L1 only) H1(t-2)
    f4 a0x;                        // L0: bias0 + Wih0@x(t), one step ahead
    float2 xb[SS];                 // rolling x prefetch (L0 only)
    if (L0) {
        const float2 x0 = *(const float2*)xrow;
        F8 xf; xf.p[0] = pkrtz(x0.x, x0.y); xf.p[1] = z2; xf.p[2] = z2; xf.p[3] = z2;
        a0x = MFMA(wi0, xf.v, biasc);
        #pragma unroll
        for (int i = 0; i < SS; ++i) {
            int tn = i + 1; if (tn > T_STEPS - 1) tn = T_STEPS - 1;
            xb[i] = *(const float2*)(xrow + tn * IN0);
        }
    }

    for (int s = 0; s < NSS; ++s) {
        #pragma unroll
        for (int i = 0; i < SS; ++i) {
            const int t = SS * s + i;
            const int bf = t & 1;
            if (L0) {
                // H0(t) = tanh(a0x + Whh0@H0(t-1)); independent accumulators
                f4 p0 = MFMA(wa[0], h0f[0], a0x);
                f4 p1 = MFMA(wa[1], h0f[1], zero);
                const f4 a0 = p0 + p1;
                H4U u;
                u.p[0] = pkrtz(tanh_fast(a0[0]), tanh_fast(a0[1]));
                u.p[1] = pkrtz(tanh_fast(a0[2]), tanh_fast(a0[3]));
                H0c[bf][wc][n] = u.v;
                // a0x(t+1) — off the chain; rolling refill (7 steps to land)
                F8 xf; xf.p[0] = pkrtz(xb[i].x, xb[i].y);
                xf.p[1] = z2; xf.p[2] = z2; xf.p[3] = z2;
                a0x = MFMA(wi0, xf.v, biasc);
                int tn = t + 1 + SS; if (tn > T_STEPS - 1) tn = T_STEPS - 1;
                xb[i] = *(const float2*)(xrow + tn * IN0);
            } else {
                // H1(t-1) = tanh(b1 + Wih1@H0(t-1) + Whh1@H1(t-2))
                f4 c0 = MFMA(wa[0], h0f[0], biasc);
                f4 c1 = MFMA(wa[1], h0f[1], zero);
                f4 c2 = MFMA(wb[0], h1f[0], zero);
                f4 c3 = MFMA(wb[1], h1f[1], zero);
                const f4 a1 = (c0 + c1) + (c2 + c3);
                H4U u;
                u.p[0] = pkrtz(tanh_fast(a1[0]), tanh_fast(a1[1]));
                u.p[1] = pkrtz(tanh_fast(a1[2]), tanh_fast(a1[3]));
                if (t == 0) { u.p[0] = z2; u.p[1] = z2; }   // true H1(-1)=0
                H1c[bf][wc][n] = u.v;
            }
            LDS_BARRIER();
            // B-frags: k-tile kt chunks 8kt+2q, 8kt+2q+1 (adjacent, read2-able)
            {
                H8U b0, b1;
                b0.h[0] = H0c[bf][2 * q][n];     b0.h[1] = H0c[bf][2 * q + 1][n];
                b1.h[0] = H0c[bf][8 + 2 * q][n]; b1.h[1] = H0c[bf][9 + 2 * q][n];
                h0f[0] = b0.v; h0f[1] = b1.v;
            }
            if (!L0) {
                H8U b0, b1;
                b0.h[0] = H1c[bf][2 * q][n];     b0.h[1] = H1c[bf][2 * q + 1][n];
                b1.h[0] = H1c[bf][8 + 2 * q][n]; b1.h[1] = H1c[bf][9 + 2 * q][n];
                h1f[0] = b0.v; h1f[1] = b1.v;
            }
        }
    }

    // ---- epilogue: H1(511) from h0f=H0(511), h1f=H1(510); FC head ----
    if (!L0) {
        f4 c0 = MFMA(wa[0], h0f[0], biasc);
        f4 c1 = MFMA(wa[1], h0f[1], zero);
        f4 c2 = MFMA(wb[0], h1f[0], zero);
        f4 c3 = MFMA(wb[1], h1f[1], zero);
        const f4 a1 = (c0 + c1) + (c2 + c3);
        float sacc = 0.f;
        #pragma unroll
        for (int r = 0; r < 4; ++r) sacc += fcv[r] * tanh_fast(a1[r]);
        sacc += __shfl_xor(sacc, 16, 64);
        sacc += __shfl_xor(sacc, 32, 64);
        if (lane < 16) red[mt][n] = sacc;    // q==0 lanes
    }
    __syncthreads();
    if (tid < SPW)
        out[bseq + tid] = red[0][tid] + red[1][tid] + red[2][tid] + red[3][tid] + fcb0;
}

extern "C" void kernel_launch(void* const* d_in, const int* in_sizes, int n_in,
                              void* d_out, int out_size, void* d_ws, size_t ws_size,
                              hipStream_t stream) {
    const float* x    = (const float*)d_in[0];
    const float* Wih0 = (const float*)d_in[1];
    const float* Whh0 = (const float*)d_in[2];
    const float* bih0 = (const float*)d_in[3];
    const float* bhh0 = (const float*)d_in[4];
    const float* Wih1 = (const float*)d_in[5];
    const float* Whh1 = (const float*)d_in[6];
    const float* bih1 = (const float*)d_in[7];
    const float* bhh1 = (const float*)d_in[8];
    const float* fcw  = (const float*)d_in[9];
    const float* fcb  = (const float*)d_in[10];
    float* out = (float*)d_out;

    rnn2_cf<<<dim3(NBLK), dim3(512), 0, stream>>>(
        x, Wih0, Whh0, bih0, bhh0, Wih1, Whh1, bih1, bhh1, fcw, fcb, out);
}